// Round 10
// baseline (801.533 us; speedup 1.0000x reference)
//
#include <hip/hip_runtime.h>

// B=2, S=2048, D=2048, H=16, KV=8, HD=128, N_REP=2.
// I/O: fp32. Compute: bf16 MFMA, fp32 accum.
//
// Pipeline (5 launches):
//   1. prep: cvt x->bf16  +  Wq/Wk/Wv/Wo transposes        (merged)
//   2. gemm256sb: QKV = xb @ WqkvT  (256x256, BK=64, SINGLE-buffer 64KB LDS
//      at quarter/region granularity -> 2 blocks/CU, counted vmcnt(2))
//   3. mid: RoPE on Q,K  +  V transpose -> Vt              (merged)
//   4. flash v9: 8-wave blocks + CU-balanced qt map
//   5. gemm256x128: out = Ab @ WoT  (256x128 tile -> 256 blocks)

typedef __bf16 bf16;
typedef __bf16 bf16x4 __attribute__((ext_vector_type(4)));
typedef __bf16 bf16x8 __attribute__((ext_vector_type(8)));
typedef float floatx4 __attribute__((ext_vector_type(4)));

#define AS1(p) ((const __attribute__((address_space(1))) void*)(p))
#define AS3(p) ((__attribute__((address_space(3))) void*)(p))

__device__ __forceinline__ void load16(const void* g, void* l) {
  __builtin_amdgcn_global_load_lds(AS1(g), AS3(l), 16, 0, 0);
}

__device__ __forceinline__ void phase_barrier() {
  asm volatile("" ::: "memory");
  __builtin_amdgcn_sched_barrier(0);
  __builtin_amdgcn_s_barrier();
  __builtin_amdgcn_sched_barrier(0);
  asm volatile("" ::: "memory");
}

// ---------------- prep: cvt (blocks 0..8191) + 4 weight transposes ----------------
__global__ __launch_bounds__(256) void prep_kernel(
    const float* __restrict__ x, const float* __restrict__ Wq,
    const float* __restrict__ Wk, const float* __restrict__ Wv,
    const float* __restrict__ Wo, bf16* __restrict__ xb,
    bf16* __restrict__ WqkvT, bf16* __restrict__ WoT) {
  __shared__ float tile[32][33];
  const int bi = blockIdx.x;
  if (bi < 8192) {
    int i = bi * 256 + threadIdx.x;  // n4 = 2097152 = 8192*256 exactly
    float4 v = ((const float4*)x)[i];
    bf16x4 o = {(bf16)v.x, (bf16)v.y, (bf16)v.z, (bf16)v.w};
    ((bf16x4*)xb)[i] = o;
    return;
  }
  const int i2 = bi - 8192;
  const int wid = i2 >> 12;               // 0..3
  const int r0 = ((i2 >> 6) & 63) * 32;
  const int c0 = (i2 & 63) * 32;
  const float* src = wid == 0 ? Wq : wid == 1 ? Wk : wid == 2 ? Wv : Wo;
  bf16* dst = wid == 0 ? WqkvT
            : wid == 1 ? WqkvT + 2048ull * 2048
            : wid == 2 ? WqkvT + 3072ull * 2048
                       : WoT;
  const int ncols = (wid == 1 || wid == 2) ? 1024 : 2048;
  if (c0 >= ncols) return;
  const int tx = threadIdx.x & 31, ty = threadIdx.x >> 5;  // 32 x 8
#pragma unroll
  for (int i = 0; i < 4; i++) {
    int ri = ty + i * 8;
    tile[ri][tx] = src[(long)(r0 + ri) * ncols + c0 + tx];
  }
  __syncthreads();
#pragma unroll
  for (int i = 0; i < 4; i++) {
    int ci = ty + i * 8;
    dst[(long)(c0 + ci) * 2048 + r0 + tx] = (bf16)tile[tx][ci];
  }
}

// ---------------- mid: RoPE (blocks 0..24575) + V transpose ----------------
__global__ __launch_bounds__(256) void mid_kernel(
    bf16* __restrict__ QKV, const float* __restrict__ cosb,
    const float* __restrict__ sinb, bf16* __restrict__ Vtb) {
  __shared__ bf16 tile[32][33];
  const int bi = blockIdx.x;
  if (bi < 24576) {
    int idx = bi * 256 + threadIdx.x;  // 6291456 = 24576*256 exactly
    int nh, nhs, offc;
    if (idx < 4194304) { nh = 16; nhs = 4; offc = 0; }
    else { idx -= 4194304; nh = 8; nhs = 3; offc = 2048; }
    int d = idx & 63;
    int rest = idx >> 6;
    int hh = rest & (nh - 1);
    int bs = rest >> nhs;  // b*2048 + s
    int s = bs & 2047;
    size_t base = (size_t)bs * 4096 + offc + hh * 128;
    float c0 = cosb[s * 128 + d];
    float c1 = cosb[s * 128 + d + 64];
    float s0 = sinb[s * 128 + d];
    float s1 = sinb[s * 128 + d + 64];
    float x0 = (float)QKV[base + d];
    float x1 = (float)QKV[base + d + 64];
    QKV[base + d] = (bf16)(x0 * c0 - x1 * s0);
    QKV[base + d + 64] = (bf16)(x1 * c1 + x0 * s1);
    return;
  }
  // V transpose: per batch [2048 s][1024 c] -> [1024 c][2048 s]
  const int i2 = bi - 24576;          // 0..4095
  const int z = i2 >> 11;             // batch
  const int r0 = ((i2 >> 5) & 63) * 32;  // s
  const int c0 = (i2 & 31) * 32;         // col within V (0..1023)
  const bf16* in = QKV + 3072;
  const long ib = 2048ll * 4096 * z, ob = 1024ll * 2048 * z;
  const int tx = threadIdx.x & 31, ty = threadIdx.x >> 5;
#pragma unroll
  for (int i = 0; i < 4; i++) {
    int ri = ty + i * 8;
    tile[ri][tx] = in[ib + (long)(r0 + ri) * 4096 + c0 + tx];
  }
  __syncthreads();
#pragma unroll
  for (int i = 0; i < 4; i++) {
    int ci = ty + i * 8;
    Vtb[ob + (long)(c0 + ci) * 2048 + r0 + tx] = tile[tx][ci];
  }
}

// ---------------- GEMM 256x256 single-buffer: C[M,N] = A[M,K] * Bt[N,K]^T ----------------
// 512 threads = 8 waves (wm = wave>>2, wn = wave&3). Per-wave output 128x64.
// LDS 64 KB (-> 2 blocks/CU, two independent barrier domains):
//   A quarters q0..q3 (64 rows x 64 K, 8 KB) at q*8192
//   B regions  r0..r3 (64 cols x 64 K, 8 KB) at 32768 + r*8192
// Quadrant phase order makes single-buffering legal (reads of a sub-tile are
// register-retired before its phase-end barrier):
//   P1 reads Aq0/q2 + B fc01  -> stage nothing
//   P2 reads B fc23           -> stage Aq0,Aq2(t+1);  vmcnt(2) [drains Aq1,Aq3(t)]
//   P3 reads Aq1/q3           -> stage Br0-3(t+1)
//   P4 (register reuse only)  -> stage Aq1,Aq3(t+1);  vmcnt(2) [drains Aq0,Aq2,Br0-3(t+1)]
// Steady state: 8 loads/wave outstanding max; final tile uses vmcnt(0) at P2.
// Requires M%256==0, N%256==0, K%64==0.
template <typename CT>
__global__ __launch_bounds__(512, 4) void gemm256sb(
    const bf16* __restrict__ A, const bf16* __restrict__ Bt, CT* __restrict__ C,
    int M, int N, int K) {
  __shared__ __align__(1024) char smem[65536];
  const int tid = threadIdx.x;
  const int wave = tid >> 6, lane = tid & 63;
  const int quad = lane >> 4, l16 = lane & 15;
  const int wm = wave >> 2, wn = wave & 3;
  const int m0 = blockIdx.y * 256, n0 = blockIdx.x * 256;

  // staging: one load16 per thread covers one 8KB quarter/region; global source
  // inverse-swizzled (same st_16x32 involution as reads).
  const int srow = (wave >> 1) * 16 + (lane >> 2);  // 0..63 within sub-tile
  const int skcol = (wave & 1) * 32 + (((lane & 3) * 8) ^ ((lane & 32) ? 16 : 0));
  const int sblk = wave * 1024;

  // fragment-read offsets (swizzled); layout identical to the dbuf version.
  const int qoff = (quad * 16) ^ ((l16 & 8) << 2);
  const int aoff = wm * 16384 + l16 * 64 + qoff;
  const int boff = 32768 + wn * 8192 + l16 * 64 + qoff;

  auto stageAq = [&](int kt, int q) {
    const bf16* g = A + (size_t)(m0 + q * 64 + srow) * K + kt * 64 + skcol;
    load16(g, smem + q * 8192 + sblk);
  };
  auto stageBr = [&](int kt, int r) {
    const bf16* g = Bt + (size_t)(n0 + r * 64 + srow) * K + kt * 64 + skcol;
    load16(g, smem + 32768 + r * 8192 + sblk);
  };
  auto rdA = [&](int fr, int ks) {
    return *(const bf16x8*)(smem + aoff + (fr * 2 + ks) * 1024);
  };
  auto rdB = [&](int fc, int ks) {
    return *(const bf16x8*)(smem + boff + (fc * 2 + ks) * 1024);
  };

  floatx4 acc[8][4] = {};
  const int nkt = K >> 6;

  // prologue: tile 0 (8 loads); drain all but Aq1,Aq3 (needed at P3)
  stageAq(0, 0); stageAq(0, 2);
  stageBr(0, 0); stageBr(0, 1); stageBr(0, 2); stageBr(0, 3);
  stageAq(0, 1); stageAq(0, 3);
  asm volatile("s_waitcnt vmcnt(2)" ::: "memory");
  phase_barrier();

  for (int t = 0; t < nkt; ++t) {
    const bool morek = (t + 1 < nkt);
    bf16x8 a[4][2], b01[2][2], b23[2][2];

    // ---- P1: Q(0,0) = A rows 0-63 (own half) x B cols 0-31 (own region) ----
#pragma unroll
    for (int fr = 0; fr < 4; ++fr)
#pragma unroll
      for (int ks = 0; ks < 2; ++ks) a[fr][ks] = rdA(fr, ks);
#pragma unroll
    for (int fc = 0; fc < 2; ++fc)
#pragma unroll
      for (int ks = 0; ks < 2; ++ks) b01[fc][ks] = rdB(fc, ks);
    phase_barrier();
    __builtin_amdgcn_s_setprio(1);
#pragma unroll
    for (int ks = 0; ks < 2; ++ks)
#pragma unroll
      for (int fr = 0; fr < 4; ++fr)
#pragma unroll
        for (int fc = 0; fc < 2; ++fc)
          acc[fr][fc] = __builtin_amdgcn_mfma_f32_16x16x32_bf16(
              a[fr][ks], b01[fc][ks], acc[fr][fc], 0, 0, 0);
    __builtin_amdgcn_s_setprio(0);
    phase_barrier();

    // ---- P2: Q(0,1); stage Aq0,Aq2(t+1) (dest dead since P1 barrier) ----
#pragma unroll
    for (int fc = 0; fc < 2; ++fc)
#pragma unroll
      for (int ks = 0; ks < 2; ++ks) b23[fc][ks] = rdB(2 + fc, ks);
    if (morek) { stageAq(t + 1, 0); stageAq(t + 1, 2); }
    if (morek)
      asm volatile("s_waitcnt vmcnt(2)" ::: "memory");  // drains Aq1,Aq3(t)
    else
      asm volatile("s_waitcnt vmcnt(0)" ::: "memory");
    phase_barrier();
    __builtin_amdgcn_s_setprio(1);
#pragma unroll
    for (int ks = 0; ks < 2; ++ks)
#pragma unroll
      for (int fr = 0; fr < 4; ++fr)
#pragma unroll
        for (int fc = 0; fc < 2; ++fc)
          acc[fr][2 + fc] = __builtin_amdgcn_mfma_f32_16x16x32_bf16(
              a[fr][ks], b23[fc][ks], acc[fr][2 + fc], 0, 0, 0);
    __builtin_amdgcn_s_setprio(0);
    phase_barrier();

    // ---- P3: Q(1,1); stage Br0-3(t+1) (regions dead since P2 barrier) ----
#pragma unroll
    for (int fr = 0; fr < 4; ++fr)
#pragma unroll
      for (int ks = 0; ks < 2; ++ks) a[fr][ks] = rdA(4 + fr, ks);
    if (morek) {
      stageBr(t + 1, 0); stageBr(t + 1, 1); stageBr(t + 1, 2); stageBr(t + 1, 3);
    }
    phase_barrier();
    __builtin_amdgcn_s_setprio(1);
#pragma unroll
    for (int ks = 0; ks < 2; ++ks)
#pragma unroll
      for (int fr = 0; fr < 4; ++fr)
#pragma unroll
        for (int fc = 0; fc < 2; ++fc)
          acc[4 + fr][2 + fc] = __builtin_amdgcn_mfma_f32_16x16x32_bf16(
              a[fr][ks], b23[fc][ks], acc[4 + fr][2 + fc], 0, 0, 0);
    __builtin_amdgcn_s_setprio(0);
    phase_barrier();

    // ---- P4: Q(1,0) (b01 from registers); stage Aq1,Aq3(t+1) ----
    if (morek) {
      stageAq(t + 1, 1); stageAq(t + 1, 3);
      asm volatile("s_waitcnt vmcnt(2)" ::: "memory");  // drains Aq0,Aq2,Br0-3(t+1)
    }
    phase_barrier();
    __builtin_amdgcn_s_setprio(1);
#pragma unroll
    for (int ks = 0; ks < 2; ++ks)
#pragma unroll
      for (int fr = 0; fr < 4; ++fr)
#pragma unroll
        for (int fc = 0; fc < 2; ++fc)
          acc[4 + fr][fc] = __builtin_amdgcn_mfma_f32_16x16x32_bf16(
              a[fr][ks], b01[fc][ks], acc[4 + fr][fc], 0, 0, 0);
    __builtin_amdgcn_s_setprio(0);
    phase_barrier();
  }

  // epilogue
#pragma unroll
  for (int fr = 0; fr < 8; ++fr)
#pragma unroll
    for (int fc = 0; fc < 4; ++fc)
#pragma unroll
      for (int r = 0; r < 4; ++r) {
        int row = m0 + wm * 128 + fr * 16 + quad * 4 + r;
        int col = n0 + wn * 64 + fc * 16 + l16;
        C[(size_t)row * N + col] = (CT)acc[fr][fc][r];
      }
}

// ---------------- GEMM 256x128, 8-phase (out-projection, fp32 C) ----------------
// 8 waves as 4M x 2N, per-wave 64x64 = acc[4][4]. LDS/buffer 48KB dbuf = 96KB.
// vmcnt(2) at P4 leaves only the newest B half-tile in flight.
__global__ __launch_bounds__(512, 1) void gemm256x128(
    const bf16* __restrict__ A, const bf16* __restrict__ Bt, float* __restrict__ C,
    int M, int N, int K) {
  __shared__ __align__(1024) char smem[98304];
  const int tid = threadIdx.x;
  const int wave = tid >> 6, lane = tid & 63;
  const int quad = lane >> 4, l16 = lane & 15;
  const int wm = wave >> 1, wn = wave & 1;  // 4 x 2 wave grid, wave tile 64x64
  const int m0 = blockIdx.y * 256, n0 = blockIdx.x * 128;

  const int srow = (wave >> 1) * 16 + (lane >> 2);
  const int skcol = (wave & 1) * 32 + (((lane & 3) * 8) ^ ((lane & 32) ? 16 : 0));
  const int sblk = wave * 1024;

  const int qoff = (quad * 16) ^ ((l16 & 8) << 2);
  const int aoff = (wm >> 1) * 16384 + l16 * 64 + qoff;  // half select
  const int afrag = (wm & 1) * 4;                        // frag base within half
  const int boff = 32768 + l16 * 64 + qoff;
  const int bfrag = wn * 4;

  auto stageA = [&](int kt, int h, int buf) {
    const bf16* g = A + (size_t)(m0 + h * 128 + srow) * K + kt * 64 + skcol;
    char* d = smem + buf * 49152 + h * 16384 + sblk;
    load16(g, d);
    load16(g + (size_t)64 * K, d + 8192);
  };
  auto stageB = [&](int kt, int buf) {
    const bf16* g = Bt + (size_t)(n0 + srow) * K + kt * 64 + skcol;
    char* d = smem + buf * 49152 + 32768 + sblk;
    load16(g, d);
    load16(g + (size_t)64 * K, d + 8192);
  };
  auto rdA = [&](int buf, int fr, int ks) {
    return *(const bf16x8*)(smem + buf * 49152 + aoff + ((afrag + fr) * 2 + ks) * 1024);
  };
  auto rdB = [&](int buf, int fc, int ks) {
    return *(const bf16x8*)(smem + buf * 49152 + boff + ((bfrag + fc) * 2 + ks) * 1024);
  };

  floatx4 acc[4][4] = {};

  const int nkt = K >> 6;
  const int niter = nkt >> 1;

  // prologue: tile0 -> buf0 (B 2 + A 4), tile1 B -> buf1 (2); drain tile0
  stageB(0, 0);
  stageA(0, 0, 0); stageA(0, 1, 0);
  stageB(1, 1);
  asm volatile("s_waitcnt vmcnt(2)" ::: "memory");
  phase_barrier();

  for (int it = 0; it < niter; ++it) {
    const int T = 2 * it;
    const bool morek = (it < niter - 1);
#pragma unroll
    for (int c = 0; c < 2; ++c) {
      const int buf = c;
      const int tA = T + 1 + c;
      const int tB = T + 2 + c;
      const bool stA = (c == 0) || morek;

      bf16x8 a[2][2], b01[2][2], b23[2][2];

      // ---- phase 1: A frags 0-1 x B frags 0-1 ----
#pragma unroll
      for (int fr = 0; fr < 2; ++fr)
#pragma unroll
        for (int ks = 0; ks < 2; ++ks) a[fr][ks] = rdA(buf, fr, ks);
#pragma unroll
      for (int fc = 0; fc < 2; ++fc)
#pragma unroll
        for (int ks = 0; ks < 2; ++ks) b01[fc][ks] = rdB(buf, fc, ks);
      if (stA) stageA(tA, 0, buf ^ 1);
      phase_barrier();
      __builtin_amdgcn_s_setprio(1);
#pragma unroll
      for (int ks = 0; ks < 2; ++ks)
#pragma unroll
        for (int fr = 0; fr < 2; ++fr)
#pragma unroll
          for (int fc = 0; fc < 2; ++fc)
            acc[fr][fc] = __builtin_amdgcn_mfma_f32_16x16x32_bf16(
                a[fr][ks], b01[fc][ks], acc[fr][fc], 0, 0, 0);
      __builtin_amdgcn_s_setprio(0);
      phase_barrier();

      // ---- phase 2: A frags 0-1 x B frags 2-3 ----
#pragma unroll
      for (int fc = 0; fc < 2; ++fc)
#pragma unroll
        for (int ks = 0; ks < 2; ++ks) b23[fc][ks] = rdB(buf, 2 + fc, ks);
      if (stA) stageA(tA, 1, buf ^ 1);
      phase_barrier();
      __builtin_amdgcn_s_setprio(1);
#pragma unroll
      for (int ks = 0; ks < 2; ++ks)
#pragma unroll
        for (int fr = 0; fr < 2; ++fr)
#pragma unroll
          for (int fc = 0; fc < 2; ++fc)
            acc[fr][2 + fc] = __builtin_amdgcn_mfma_f32_16x16x32_bf16(
                a[fr][ks], b23[fc][ks], acc[fr][2 + fc], 0, 0, 0);
      __builtin_amdgcn_s_setprio(0);
      phase_barrier();

      // ---- phase 3: A frags 2-3 x B frags 2-3 ----
#pragma unroll
      for (int fr = 0; fr < 2; ++fr)
#pragma unroll
        for (int ks = 0; ks < 2; ++ks) a[fr][ks] = rdA(buf, 2 + fr, ks);
      if (morek) stageB(tB, buf);
      phase_barrier();
      __builtin_amdgcn_s_setprio(1);
#pragma unroll
      for (int ks = 0; ks < 2; ++ks)
#pragma unroll
        for (int fr = 0; fr < 2; ++fr)
#pragma unroll
          for (int fc = 0; fc < 2; ++fc)
            acc[2 + fr][2 + fc] = __builtin_amdgcn_mfma_f32_16x16x32_bf16(
                a[fr][ks], b23[fc][ks], acc[2 + fr][2 + fc], 0, 0, 0);
      __builtin_amdgcn_s_setprio(0);
      phase_barrier();

      // ---- phase 4: A frags 2-3 x B frags 0-1 ----
      if (morek)
        asm volatile("s_waitcnt vmcnt(2)" ::: "memory");
      else
        asm volatile("s_waitcnt vmcnt(0)" ::: "memory");
      phase_barrier();
      __builtin_amdgcn_s_setprio(1);
#pragma unroll
      for (int ks = 0; ks < 2; ++ks)
#pragma unroll
        for (int fr = 0; fr < 2; ++fr)
#pragma unroll
          for (int fc = 0; fc < 2; ++fc)
            acc[2 + fr][fc] = __builtin_amdgcn_mfma_f32_16x16x32_bf16(
                a[fr][ks], b01[fc][ks], acc[2 + fr][fc], 0, 0, 0);
      __builtin_amdgcn_s_setprio(0);
      phase_barrier();
    }
  }

#pragma unroll
  for (int fr = 0; fr < 4; ++fr)
#pragma unroll
    for (int fc = 0; fc < 4; ++fc)
#pragma unroll
      for (int r = 0; r < 4; ++r) {
        int row = m0 + wm * 64 + fr * 16 + quad * 4 + r;
        int col = n0 + wn * 64 + fc * 16 + l16;
        C[(size_t)row * N + col] = acc[fr][fc][r];
      }
}

// ---------------- Flash v9: 8-wave blocks + CU-balanced qt map ----------------
// (unchanged from round 9 — balanced under co-CU strides +8/+16/+256)
template <bool MASK>
__device__ __forceinline__ void attn_step32(
    const bf16* Kc, const bf16* Vc, bf16* Pw, const bf16x8 (&aq)[4],
    const bf16x8& ones, floatx4 (&oacc)[8], floatx4& lacc,
    int k0, int q0w, int l16, int quad) {
  floatx4 sacc[4] = {};
  __builtin_amdgcn_s_setprio(1);
#pragma unroll
  for (int ks = 0; ks < 4; ks++)
#pragma unroll
    for (int j = 0; j < 4; j++) {
      int row = j * 16 + l16;
      bf16x8 bk = *(const bf16x8*)(Kc + row * 128 + (((ks * 4 + quad) ^ (row & 15)) * 8));
      sacc[j] = __builtin_amdgcn_mfma_f32_16x16x32_bf16(aq[ks], bk, sacc[j], 0, 0, 0);
    }
  __builtin_amdgcn_s_setprio(0);
  const float C = 0.12752188659023044f;  // (1/sqrt(128)) * log2(e)
#pragma unroll
  for (int r = 0; r < 4; r++) {
    int row = quad * 4 + r;
#pragma unroll
    for (int j = 0; j < 4; j++) {
      float p = exp2f(sacc[j][r] * C);
      if (MASK) {
        int key = k0 + j * 16 + l16;
        if (key > q0w + row) p = 0.f;
      }
      int col = j * 16 + l16;
      Pw[row * 64 + (((col >> 3) ^ (row & 7)) * 8) + (col & 7)] = (bf16)p;
    }
  }
  __builtin_amdgcn_s_setprio(1);
#pragma unroll
  for (int ks = 0; ks < 2; ks++) {
    bf16x8 ap = *(const bf16x8*)(Pw + l16 * 64 + (((ks * 4 + quad) ^ (l16 & 7)) * 8));
    lacc = __builtin_amdgcn_mfma_f32_16x16x32_bf16(ap, ones, lacc, 0, 0, 0);
#pragma unroll
    for (int j = 0; j < 8; j++) {
      int vr = j * 16 + l16;
      bf16x8 bv = *(const bf16x8*)(Vc + vr * 64 + (((ks * 4 + quad) ^ (vr & 7)) * 8));
      oacc[j] = __builtin_amdgcn_mfma_f32_16x16x32_bf16(ap, bv, oacc[j], 0, 0, 0);
    }
  }
  __builtin_amdgcn_s_setprio(0);
}

__global__ __launch_bounds__(512, 4) void flash_kernel(
    const bf16* __restrict__ QKV, const bf16* __restrict__ Vt, bf16* __restrict__ O) {
  __shared__ __align__(1024) char smem[81920];
  const int tid = threadIdx.x;
  const int wave = tid >> 6, lane = tid & 63, quad = lane >> 4, l16 = lane & 15;
  const int wbase = tid & ~63;
  const int hloc = wave & 1, rgroup = wave >> 1;
  bf16* Pw = (bf16*)(smem + 65536) + wave * 1024;
  bf16x8 ones;
#pragma unroll
  for (int e = 0; e < 8; e++) ones[e] = (bf16)1.0f;

  const int w = blockIdx.x;
  const int side = w & 1, kvh = (w >> 1) & 7, b = (w >> 4) & 1, g = w >> 5;
  const int p = (g < 8) ? (2 * g + side) : (31 - 2 * (g - 8) - side);
  const int qt = (((kvh >> 2) ^ b) & 1) ? 31 - p : p;
  const int h = kvh * 2 + hloc;
  const int q0 = qt * 64;
  const int nkt = qt + 1;

#pragma unroll
  for (int u = 0; u < 4; u++) {
    int gg = u * 512 + tid;
    int row = gg >> 4, cc = gg & 15;
    const bf16* gp = QKV + (size_t)(b * 2048 + q0 + (row & 63)) * 4096 +
                     (kvh * 2 + (row >> 6)) * 128 + ((cc ^ (row & 15)) * 8);
    load16(gp, smem + (u * 512 + wbase) * 16);
  }
  asm volatile("s_waitcnt vmcnt(0)" ::: "memory");
  phase_barrier();
  bf16x8 aq[4];
  {
    int qr = hloc * 64 + rgroup * 16 + l16;
#pragma unroll
    for (int ks = 0; ks < 4; ks++)
      aq[ks] = *(const bf16x8*)((const bf16*)smem + qr * 128 +
                                (((ks * 4 + quad) ^ (qr & 15)) * 8));
  }
  __syncthreads();

  auto stageKV = [&](int kt, int nb) {
    char* kd = smem + nb * 16384;
    char* vd = smem + 32768 + nb * 16384;
#pragma unroll
    for (int u = 0; u < 2; u++) {
      int gg = u * 512 + tid;
      int krow = gg >> 4, kcc = gg & 15;
      const bf16* kp = QKV + (size_t)(b * 2048 + kt * 64 + krow) * 4096 + 2048 +
                       kvh * 128 + ((kcc ^ (krow & 15)) * 8);
      load16(kp, kd + (u * 512 + wbase) * 16);
      int vrow = gg >> 3, vcc = gg & 7;
      const bf16* vp = Vt + (size_t)(b * 1024 + kvh * 128 + vrow) * 2048 + kt * 64 +
                       ((vcc ^ (vrow & 7)) * 8);
      load16(vp, vd + (u * 512 + wbase) * 16);
    }
  };

  stageKV(0, 0);

  floatx4 oacc[8] = {};
  floatx4 lacc = {};
  const int q0w = q0 + rgroup * 16;

  for (int kt = 0; kt < nkt; kt++) {
    const int cur = kt & 1;
    if (kt + 1 < nkt) {
      stageKV(kt + 1, cur ^ 1);
      asm volatile("s_waitcnt vmcnt(4)" ::: "memory");
    } else {
      asm volatile("s_waitcnt vmcnt(0)" ::: "memory");
    }
    phase_barrier();
    const bf16* Kc = (const bf16*)(smem + cur * 16384);
    const bf16* Vc = (const bf16*)(smem + 32768 + cur * 16384);
    if (kt == nkt - 1)
      attn_step32<true>(Kc, Vc, Pw, aq, ones, oacc, lacc, kt * 64, q0w, l16, quad);
    else
      attn_step32<false>(Kc, Vc, Pw, aq, ones, oacc, lacc, kt * 64, q0w, l16, quad);
    phase_barrier();
  }

  float rl[4];
#pragma unroll
  for (int r = 0; r < 4; r++) rl[r] = 1.0f / lacc[r];
#pragma unroll
  for (int j = 0; j < 8; j++)
#pragma unroll
    for (int r = 0; r < 4; r++) {
      int s = q0w + quad * 4 + r;
      O[(size_t)(b * 2048 + s) * 2048 + h * 128 + j * 16 + l16] =
          (bf16)(oacc[j][r] * rl[r]);
    }
}

extern "C" void kernel_launch(void* const* d_in, const int* in_sizes, int n_in,
                              void* d_out, int out_size, void* d_ws, size_t ws_size,
                              hipStream_t stream) {
  (void)in_sizes; (void)n_in; (void)out_size; (void)ws_size;
  const float* x    = (const float*)d_in[0];
  const float* cosb = (const float*)d_in[1];
  const float* sinb = (const float*)d_in[2];
  const float* Wq   = (const float*)d_in[3];
  const float* Wk   = (const float*)d_in[4];
  const float* Wv   = (const float*)d_in[5];
  const float* Wo   = (const float*)d_in[6];
  float* out = (float*)d_out;

  char* ws = (char*)d_ws;
  size_t off = 0;
  auto alloc = [&](size_t bytes) { void* p = ws + off; off += bytes; return p; };
  bf16* xb    = (bf16*)alloc(4096ull * 2048 * 2);  // 16 MB
  bf16* WqkvT = (bf16*)alloc(4096ull * 2048 * 2);  // 16 MB  [Wq^T | Wk^T | Wv^T]
  bf16* WoT   = (bf16*)alloc(2048ull * 2048 * 2);  //  8 MB
  bf16* QKV   = (bf16*)alloc(4096ull * 4096 * 2);  // 32 MB  [s][Q 2048 | K 1024 | V 1024]
  bf16* Vtb   = (bf16*)alloc(2048ull * 2048 * 2);  //  8 MB  [b][kv*128+hd][s]
  bf16* Ab    = (bf16*)alloc(4096ull * 2048 * 2);  // 16 MB

  // 1. cvt + weight transposes (merged)
  prep_kernel<<<8192 + 16384, 256, 0, stream>>>(x, Wq, Wk, Wv, Wo, xb, WqkvT, WoT);

  // 2. fused QKV projection: single-buffer 64KB LDS -> 2 blocks/CU
  gemm256sb<bf16><<<dim3(16, 16), 512, 0, stream>>>(xb, WqkvT, QKV, 4096, 4096, 2048);

  // 3. RoPE + V transpose (merged)
  mid_kernel<<<24576 + 4096, 256, 0, stream>>>(QKV, cosb, sinb, Vtb);

  // 4. flash attention v9: CU-balanced qt map
  flash_kernel<<<dim3(512, 1, 1), 512, 0, stream>>>(QKV, Vtb, Ab);

  // 5. output projection: 256x128 tile -> 256 blocks (full GPU)
  gemm256x128<<<dim3(16, 16), 512, 0, stream>>>(Ab, WoT, out, 4096, 2048, 2048);
}

// Round 11
// 305.069 us; speedup vs baseline: 2.6274x; 2.6274x over previous
//
#include <hip/hip_runtime.h>

// B=2, S=2048, D=2048, H=16, KV=8, HD=128, N_REP=2.
// I/O: fp32. Compute: bf16 MFMA, fp32 accum.
//
// Pipeline (5 launches):
//   1. prep: cvt x->bf16  +  Wq/Wk/Wv/Wo transposes        (merged)
//   2. gemm256ta: QKV = xb @ WqkvT  (256x256, BK=64, A TRIPLE-buffer + B dbuf,
//      160KB LDS, counted vmcnt(8): A staged 2 tiles ahead -> ~1100cy slack)
//   3. mid: RoPE on Q,K  +  V transpose -> Vt              (merged)
//   4. flash v9: 8-wave blocks + CU-balanced qt map
//   5. gemm256x128: out = Ab @ WoT  (256x128 tile -> 256 blocks)

typedef __bf16 bf16;
typedef __bf16 bf16x4 __attribute__((ext_vector_type(4)));
typedef __bf16 bf16x8 __attribute__((ext_vector_type(8)));
typedef float floatx4 __attribute__((ext_vector_type(4)));

#define AS1(p) ((const __attribute__((address_space(1))) void*)(p))
#define AS3(p) ((__attribute__((address_space(3))) void*)(p))

__device__ __forceinline__ void load16(const void* g, void* l) {
  __builtin_amdgcn_global_load_lds(AS1(g), AS3(l), 16, 0, 0);
}

__device__ __forceinline__ void phase_barrier() {
  asm volatile("" ::: "memory");
  __builtin_amdgcn_sched_barrier(0);
  __builtin_amdgcn_s_barrier();
  __builtin_amdgcn_sched_barrier(0);
  asm volatile("" ::: "memory");
}

// ---------------- prep: cvt (blocks 0..8191) + 4 weight transposes ----------------
__global__ __launch_bounds__(256) void prep_kernel(
    const float* __restrict__ x, const float* __restrict__ Wq,
    const float* __restrict__ Wk, const float* __restrict__ Wv,
    const float* __restrict__ Wo, bf16* __restrict__ xb,
    bf16* __restrict__ WqkvT, bf16* __restrict__ WoT) {
  __shared__ float tile[32][33];
  const int bi = blockIdx.x;
  if (bi < 8192) {
    int i = bi * 256 + threadIdx.x;  // n4 = 2097152 = 8192*256 exactly
    float4 v = ((const float4*)x)[i];
    bf16x4 o = {(bf16)v.x, (bf16)v.y, (bf16)v.z, (bf16)v.w};
    ((bf16x4*)xb)[i] = o;
    return;
  }
  const int i2 = bi - 8192;
  const int wid = i2 >> 12;               // 0..3
  const int r0 = ((i2 >> 6) & 63) * 32;
  const int c0 = (i2 & 63) * 32;
  const float* src = wid == 0 ? Wq : wid == 1 ? Wk : wid == 2 ? Wv : Wo;
  bf16* dst = wid == 0 ? WqkvT
            : wid == 1 ? WqkvT + 2048ull * 2048
            : wid == 2 ? WqkvT + 3072ull * 2048
                       : WoT;
  const int ncols = (wid == 1 || wid == 2) ? 1024 : 2048;
  if (c0 >= ncols) return;
  const int tx = threadIdx.x & 31, ty = threadIdx.x >> 5;  // 32 x 8
#pragma unroll
  for (int i = 0; i < 4; i++) {
    int ri = ty + i * 8;
    tile[ri][tx] = src[(long)(r0 + ri) * ncols + c0 + tx];
  }
  __syncthreads();
#pragma unroll
  for (int i = 0; i < 4; i++) {
    int ci = ty + i * 8;
    dst[(long)(c0 + ci) * 2048 + r0 + tx] = (bf16)tile[tx][ci];
  }
}

// ---------------- mid: RoPE (blocks 0..24575) + V transpose ----------------
__global__ __launch_bounds__(256) void mid_kernel(
    bf16* __restrict__ QKV, const float* __restrict__ cosb,
    const float* __restrict__ sinb, bf16* __restrict__ Vtb) {
  __shared__ bf16 tile[32][33];
  const int bi = blockIdx.x;
  if (bi < 24576) {
    int idx = bi * 256 + threadIdx.x;  // 6291456 = 24576*256 exactly
    int nh, nhs, offc;
    if (idx < 4194304) { nh = 16; nhs = 4; offc = 0; }
    else { idx -= 4194304; nh = 8; nhs = 3; offc = 2048; }
    int d = idx & 63;
    int rest = idx >> 6;
    int hh = rest & (nh - 1);
    int bs = rest >> nhs;  // b*2048 + s
    int s = bs & 2047;
    size_t base = (size_t)bs * 4096 + offc + hh * 128;
    float c0 = cosb[s * 128 + d];
    float c1 = cosb[s * 128 + d + 64];
    float s0 = sinb[s * 128 + d];
    float s1 = sinb[s * 128 + d + 64];
    float x0 = (float)QKV[base + d];
    float x1 = (float)QKV[base + d + 64];
    QKV[base + d] = (bf16)(x0 * c0 - x1 * s0);
    QKV[base + d + 64] = (bf16)(x1 * c1 + x0 * s1);
    return;
  }
  // V transpose: per batch [2048 s][1024 c] -> [1024 c][2048 s]
  const int i2 = bi - 24576;          // 0..4095
  const int z = i2 >> 11;             // batch
  const int r0 = ((i2 >> 5) & 63) * 32;  // s
  const int c0 = (i2 & 31) * 32;         // col within V (0..1023)
  const bf16* in = QKV + 3072;
  const long ib = 2048ll * 4096 * z, ob = 1024ll * 2048 * z;
  const int tx = threadIdx.x & 31, ty = threadIdx.x >> 5;
#pragma unroll
  for (int i = 0; i < 4; i++) {
    int ri = ty + i * 8;
    tile[ri][tx] = in[ib + (long)(r0 + ri) * 4096 + c0 + tx];
  }
  __syncthreads();
#pragma unroll
  for (int i = 0; i < 4; i++) {
    int ci = ty + i * 8;
    Vtb[ob + (long)(c0 + ci) * 2048 + r0 + tx] = tile[tx][ci];
  }
}

// ---------------- GEMM 256x256, A-tribuf + B-dbuf: C = A * Bt^T ----------------
// 512 threads = 8 waves (wm = wave>>2, wn = wave&3). Per-wave output 128x64,
// acc[8][4] (needs ~180 regs/wave -> (512,2), 2 waves/SIMD; do NOT raise).
// LDS 160 KB: A abuf[m]=m*32768 (m=t%3), halves h*16384;
//             B bbuf[c]=98304+c*32768 (c=t&1), halves h*16384.
// Stage map per cycle t (each stage = 2 load16/thread):
//   P1: read A fr0-3 + B fc01; stage A(t+2,h0)  [abuf[(t+2)%3] held A(t-1),
//       reads retired cycle t-1 P3 -> >=2 barriers earlier]
//   P2: read B fc23;           stage A(t+2,h1)
//   P3: read A fr4-7;          stage B(t+2,h0)  [bbuf[t&1] h0 b-reads retired P2-end]
//   P4: stage B(t+2,h1); vmcnt(8) [16 outstanding; drain tile t+1's 8]
// A slack: issued t P1, drained t+1 P4 = ~7 phases ~1100cy > HBM 900cy.
// Final tiles: t+2>=nkt -> no stage, vmcnt(0). Requires M,N%256==0, K%64==0, K>=192.
template <typename CT>
__global__ __launch_bounds__(512, 2) void gemm256ta(
    const bf16* __restrict__ A, const bf16* __restrict__ Bt, CT* __restrict__ C,
    int M, int N, int K) {
  __shared__ __align__(1024) char smem[163840];
  const int tid = threadIdx.x;
  const int wave = tid >> 6, lane = tid & 63;
  const int quad = lane >> 4, l16 = lane & 15;
  const int wm = wave >> 2, wn = wave & 3;
  const int m0 = blockIdx.y * 256, n0 = blockIdx.x * 256;

  // staging: per load-instr, wave w writes 1024B block; lane writes 16B linear;
  // global source is inverse-swizzled (st_16x32 involution).
  const int srow = (wave >> 1) * 16 + (lane >> 2);
  const int skcol = (wave & 1) * 32 + (((lane & 3) * 8) ^ ((lane & 32) ? 16 : 0));
  const int sblk = wave * 1024;

  // fragment-read offsets (swizzled); same layout as the proven dbuf kernel.
  const int qoff = (quad * 16) ^ ((l16 & 8) << 2);
  const int aoff = wm * 16384 + l16 * 64 + qoff;            // + (t%3)*32768
  const int boff = 98304 + (wn >> 1) * 16384 + (wn & 1) * 8192 + l16 * 64 + qoff;  // + (t&1)*32768

  auto stageA = [&](int kt, int h) {
    const bf16* g = A + (size_t)(m0 + h * 128 + srow) * K + kt * 64 + skcol;
    char* d = smem + (kt % 3) * 32768 + h * 16384 + sblk;
    load16(g, d);
    load16(g + (size_t)64 * K, d + 8192);
  };
  auto stageB = [&](int kt, int h) {
    const bf16* g = Bt + (size_t)(n0 + h * 128 + srow) * K + kt * 64 + skcol;
    char* d = smem + 98304 + (kt & 1) * 32768 + h * 16384 + sblk;
    load16(g, d);
    load16(g + (size_t)64 * K, d + 8192);
  };
  auto rdA = [&](int am, int fr, int ks) {
    return *(const bf16x8*)(smem + am + aoff + (fr * 2 + ks) * 1024);
  };
  auto rdB = [&](int bc, int fc, int ks) {
    return *(const bf16x8*)(smem + bc + boff + (fc * 2 + ks) * 1024);
  };

  floatx4 acc[8][4] = {};
  const int nkt = K >> 6;

  // prologue: tiles 0 and 1 fully staged (16 loads); drain tile 0's 8
  stageA(0, 0); stageA(0, 1); stageB(0, 0); stageB(0, 1);
  stageA(1, 0); stageA(1, 1); stageB(1, 0); stageB(1, 1);
  asm volatile("s_waitcnt vmcnt(8)" ::: "memory");
  phase_barrier();

  for (int t = 0; t < nkt; ++t) {
    const bool st2 = (t + 2 < nkt);
    const int am = (t % 3) * 32768;
    const int bc = (t & 1) * 32768;
    bf16x8 a[4][2], b01[2][2], b23[2][2];

    // ---- P1: Q(0,0); stage A(t+2, h0) ----
#pragma unroll
    for (int fr = 0; fr < 4; ++fr)
#pragma unroll
      for (int ks = 0; ks < 2; ++ks) a[fr][ks] = rdA(am, fr, ks);
#pragma unroll
    for (int fc = 0; fc < 2; ++fc)
#pragma unroll
      for (int ks = 0; ks < 2; ++ks) b01[fc][ks] = rdB(bc, fc, ks);
    if (st2) stageA(t + 2, 0);
    phase_barrier();
    __builtin_amdgcn_s_setprio(1);
#pragma unroll
    for (int ks = 0; ks < 2; ++ks)
#pragma unroll
      for (int fr = 0; fr < 4; ++fr)
#pragma unroll
        for (int fc = 0; fc < 2; ++fc)
          acc[fr][fc] = __builtin_amdgcn_mfma_f32_16x16x32_bf16(
              a[fr][ks], b01[fc][ks], acc[fr][fc], 0, 0, 0);
    __builtin_amdgcn_s_setprio(0);
    phase_barrier();

    // ---- P2: Q(0,1); stage A(t+2, h1) ----
#pragma unroll
    for (int fc = 0; fc < 2; ++fc)
#pragma unroll
      for (int ks = 0; ks < 2; ++ks) b23[fc][ks] = rdB(bc, 2 + fc, ks);
    if (st2) stageA(t + 2, 1);
    phase_barrier();
    __builtin_amdgcn_s_setprio(1);
#pragma unroll
    for (int ks = 0; ks < 2; ++ks)
#pragma unroll
      for (int fr = 0; fr < 4; ++fr)
#pragma unroll
        for (int fc = 0; fc < 2; ++fc)
          acc[fr][2 + fc] = __builtin_amdgcn_mfma_f32_16x16x32_bf16(
              a[fr][ks], b23[fc][ks], acc[fr][2 + fc], 0, 0, 0);
    __builtin_amdgcn_s_setprio(0);
    phase_barrier();

    // ---- P3: Q(1,1); stage B(t+2, h0) [h0 b-reads retired at P2-end] ----
#pragma unroll
    for (int fr = 0; fr < 4; ++fr)
#pragma unroll
      for (int ks = 0; ks < 2; ++ks) a[fr][ks] = rdA(am, 4 + fr, ks);
    if (st2) stageB(t + 2, 0);
    phase_barrier();
    __builtin_amdgcn_s_setprio(1);
#pragma unroll
    for (int ks = 0; ks < 2; ++ks)
#pragma unroll
      for (int fr = 0; fr < 4; ++fr)
#pragma unroll
        for (int fc = 0; fc < 2; ++fc)
          acc[4 + fr][2 + fc] = __builtin_amdgcn_mfma_f32_16x16x32_bf16(
              a[fr][ks], b23[fc][ks], acc[4 + fr][2 + fc], 0, 0, 0);
    __builtin_amdgcn_s_setprio(0);
    phase_barrier();

    // ---- P4: Q(1,0); stage B(t+2, h1); counted drain ----
    if (st2) {
      stageB(t + 2, 1);
      asm volatile("s_waitcnt vmcnt(8)" ::: "memory");  // tile t+1 fully landed
    } else {
      asm volatile("s_waitcnt vmcnt(0)" ::: "memory");
    }
    phase_barrier();
    __builtin_amdgcn_s_setprio(1);
#pragma unroll
    for (int ks = 0; ks < 2; ++ks)
#pragma unroll
      for (int fr = 0; fr < 4; ++fr)
#pragma unroll
        for (int fc = 0; fc < 2; ++fc)
          acc[4 + fr][fc] = __builtin_amdgcn_mfma_f32_16x16x32_bf16(
              a[fr][ks], b01[fc][ks], acc[4 + fr][fc], 0, 0, 0);
    __builtin_amdgcn_s_setprio(0);
    phase_barrier();
  }

  // epilogue
#pragma unroll
  for (int fr = 0; fr < 8; ++fr)
#pragma unroll
    for (int fc = 0; fc < 4; ++fc)
#pragma unroll
      for (int r = 0; r < 4; ++r) {
        int row = m0 + wm * 128 + fr * 16 + quad * 4 + r;
        int col = n0 + wn * 64 + fc * 16 + l16;
        C[(size_t)row * N + col] = (CT)acc[fr][fc][r];
      }
}

// ---------------- GEMM 256x128, 8-phase (out-projection, fp32 C) ----------------
// 8 waves as 4M x 2N, per-wave 64x64 = acc[4][4]. LDS/buffer 48KB dbuf = 96KB.
// vmcnt(2) at P4 leaves only the newest B half-tile in flight.
__global__ __launch_bounds__(512, 1) void gemm256x128(
    const bf16* __restrict__ A, const bf16* __restrict__ Bt, float* __restrict__ C,
    int M, int N, int K) {
  __shared__ __align__(1024) char smem[98304];
  const int tid = threadIdx.x;
  const int wave = tid >> 6, lane = tid & 63;
  const int quad = lane >> 4, l16 = lane & 15;
  const int wm = wave >> 1, wn = wave & 1;  // 4 x 2 wave grid, wave tile 64x64
  const int m0 = blockIdx.y * 256, n0 = blockIdx.x * 128;

  const int srow = (wave >> 1) * 16 + (lane >> 2);
  const int skcol = (wave & 1) * 32 + (((lane & 3) * 8) ^ ((lane & 32) ? 16 : 0));
  const int sblk = wave * 1024;

  const int qoff = (quad * 16) ^ ((l16 & 8) << 2);
  const int aoff = (wm >> 1) * 16384 + l16 * 64 + qoff;  // half select
  const int afrag = (wm & 1) * 4;                        // frag base within half
  const int boff = 32768 + l16 * 64 + qoff;
  const int bfrag = wn * 4;

  auto stageA = [&](int kt, int h, int buf) {
    const bf16* g = A + (size_t)(m0 + h * 128 + srow) * K + kt * 64 + skcol;
    char* d = smem + buf * 49152 + h * 16384 + sblk;
    load16(g, d);
    load16(g + (size_t)64 * K, d + 8192);
  };
  auto stageB = [&](int kt, int buf) {
    const bf16* g = Bt + (size_t)(n0 + srow) * K + kt * 64 + skcol;
    char* d = smem + buf * 49152 + 32768 + sblk;
    load16(g, d);
    load16(g + (size_t)64 * K, d + 8192);
  };
  auto rdA = [&](int buf, int fr, int ks) {
    return *(const bf16x8*)(smem + buf * 49152 + aoff + ((afrag + fr) * 2 + ks) * 1024);
  };
  auto rdB = [&](int buf, int fc, int ks) {
    return *(const bf16x8*)(smem + buf * 49152 + boff + ((bfrag + fc) * 2 + ks) * 1024);
  };

  floatx4 acc[4][4] = {};

  const int nkt = K >> 6;
  const int niter = nkt >> 1;

  // prologue: tile0 -> buf0 (B 2 + A 4), tile1 B -> buf1 (2); drain tile0
  stageB(0, 0);
  stageA(0, 0, 0); stageA(0, 1, 0);
  stageB(1, 1);
  asm volatile("s_waitcnt vmcnt(2)" ::: "memory");
  phase_barrier();

  for (int it = 0; it < niter; ++it) {
    const int T = 2 * it;
    const bool morek = (it < niter - 1);
#pragma unroll
    for (int c = 0; c < 2; ++c) {
      const int buf = c;
      const int tA = T + 1 + c;
      const int tB = T + 2 + c;
      const bool stA = (c == 0) || morek;

      bf16x8 a[2][2], b01[2][2], b23[2][2];

      // ---- phase 1: A frags 0-1 x B frags 0-1 ----
#pragma unroll
      for (int fr = 0; fr < 2; ++fr)
#pragma unroll
        for (int ks = 0; ks < 2; ++ks) a[fr][ks] = rdA(buf, fr, ks);
#pragma unroll
      for (int fc = 0; fc < 2; ++fc)
#pragma unroll
        for (int ks = 0; ks < 2; ++ks) b01[fc][ks] = rdB(buf, fc, ks);
      if (stA) stageA(tA, 0, buf ^ 1);
      phase_barrier();
      __builtin_amdgcn_s_setprio(1);
#pragma unroll
      for (int ks = 0; ks < 2; ++ks)
#pragma unroll
        for (int fr = 0; fr < 2; ++fr)
#pragma unroll
          for (int fc = 0; fc < 2; ++fc)
            acc[fr][fc] = __builtin_amdgcn_mfma_f32_16x16x32_bf16(
                a[fr][ks], b01[fc][ks], acc[fr][fc], 0, 0, 0);
      __builtin_amdgcn_s_setprio(0);
      phase_barrier();

      // ---- phase 2: A frags 0-1 x B frags 2-3 ----
#pragma unroll
      for (int fc = 0; fc < 2; ++fc)
#pragma unroll
        for (int ks = 0; ks < 2; ++ks) b23[fc][ks] = rdB(buf, 2 + fc, ks);
      if (stA) stageA(tA, 1, buf ^ 1);
      phase_barrier();
      __builtin_amdgcn_s_setprio(1);
#pragma unroll
      for (int ks = 0; ks < 2; ++ks)
#pragma unroll
        for (int fr = 0; fr < 2; ++fr)
#pragma unroll
          for (int fc = 0; fc < 2; ++fc)
            acc[fr][2 + fc] = __builtin_amdgcn_mfma_f32_16x16x32_bf16(
                a[fr][ks], b23[fc][ks], acc[fr][2 + fc], 0, 0, 0);
      __builtin_amdgcn_s_setprio(0);
      phase_barrier();

      // ---- phase 3: A frags 2-3 x B frags 2-3 ----
#pragma unroll
      for (int fr = 0; fr < 2; ++fr)
#pragma unroll
        for (int ks = 0; ks < 2; ++ks) a[fr][ks] = rdA(buf, 2 + fr, ks);
      if (morek) stageB(tB, buf);
      phase_barrier();
      __builtin_amdgcn_s_setprio(1);
#pragma unroll
      for (int ks = 0; ks < 2; ++ks)
#pragma unroll
        for (int fr = 0; fr < 2; ++fr)
#pragma unroll
          for (int fc = 0; fc < 2; ++fc)
            acc[2 + fr][2 + fc] = __builtin_amdgcn_mfma_f32_16x16x32_bf16(
                a[fr][ks], b23[fc][ks], acc[2 + fr][2 + fc], 0, 0, 0);
      __builtin_amdgcn_s_setprio(0);
      phase_barrier();

      // ---- phase 4: A frags 2-3 x B frags 0-1 ----
      if (morek)
        asm volatile("s_waitcnt vmcnt(2)" ::: "memory");
      else
        asm volatile("s_waitcnt vmcnt(0)" ::: "memory");
      phase_barrier();
      __builtin_amdgcn_s_setprio(1);
#pragma unroll
      for (int ks = 0; ks < 2; ++ks)
#pragma unroll
        for (int fr = 0; fr < 2; ++fr)
#pragma unroll
          for (int fc = 0; fc < 2; ++fc)
            acc[2 + fr][fc] = __builtin_amdgcn_mfma_f32_16x16x32_bf16(
                a[fr][ks], b01[fc][ks], acc[2 + fr][fc], 0, 0, 0);
      __builtin_amdgcn_s_setprio(0);
      phase_barrier();
    }
  }

#pragma unroll
  for (int fr = 0; fr < 4; ++fr)
#pragma unroll
    for (int fc = 0; fc < 4; ++fc)
#pragma unroll
      for (int r = 0; r < 4; ++r) {
        int row = m0 + wm * 64 + fr * 16 + quad * 4 + r;
        int col = n0 + wn * 64 + fc * 16 + l16;
        C[(size_t)row * N + col] = acc[fr][fc][r];
      }
}

// ---------------- Flash v9: 8-wave blocks + CU-balanced qt map ----------------
// (unchanged from round 9 — balanced under co-CU strides +8/+16/+256)
template <bool MASK>
__device__ __forceinline__ void attn_step32(
    const bf16* Kc, const bf16* Vc, bf16* Pw, const bf16x8 (&aq)[4],
    const bf16x8& ones, floatx4 (&oacc)[8], floatx4& lacc,
    int k0, int q0w, int l16, int quad) {
  floatx4 sacc[4] = {};
  __builtin_amdgcn_s_setprio(1);
#pragma unroll
  for (int ks = 0; ks < 4; ks++)
#pragma unroll
    for (int j = 0; j < 4; j++) {
      int row = j * 16 + l16;
      bf16x8 bk = *(const bf16x8*)(Kc + row * 128 + (((ks * 4 + quad) ^ (row & 15)) * 8));
      sacc[j] = __builtin_amdgcn_mfma_f32_16x16x32_bf16(aq[ks], bk, sacc[j], 0, 0, 0);
    }
  __builtin_amdgcn_s_setprio(0);
  const float C = 0.12752188659023044f;  // (1/sqrt(128)) * log2(e)
#pragma unroll
  for (int r = 0; r < 4; r++) {
    int row = quad * 4 + r;
#pragma unroll
    for (int j = 0; j < 4; j++) {
      float p = exp2f(sacc[j][r] * C);
      if (MASK) {
        int key = k0 + j * 16 + l16;
        if (key > q0w + row) p = 0.f;
      }
      int col = j * 16 + l16;
      Pw[row * 64 + (((col >> 3) ^ (row & 7)) * 8) + (col & 7)] = (bf16)p;
    }
  }
  __builtin_amdgcn_s_setprio(1);
#pragma unroll
  for (int ks = 0; ks < 2; ks++) {
    bf16x8 ap = *(const bf16x8*)(Pw + l16 * 64 + (((ks * 4 + quad) ^ (l16 & 7)) * 8));
    lacc = __builtin_amdgcn_mfma_f32_16x16x32_bf16(ap, ones, lacc, 0, 0, 0);
#pragma unroll
    for (int j = 0; j < 8; j++) {
      int vr = j * 16 + l16;
      bf16x8 bv = *(const bf16x8*)(Vc + vr * 64 + (((ks * 4 + quad) ^ (vr & 7)) * 8));
      oacc[j] = __builtin_amdgcn_mfma_f32_16x16x32_bf16(ap, bv, oacc[j], 0, 0, 0);
    }
  }
  __builtin_amdgcn_s_setprio(0);
}

__global__ __launch_bounds__(512, 4) void flash_kernel(
    const bf16* __restrict__ QKV, const bf16* __restrict__ Vt, bf16* __restrict__ O) {
  __shared__ __align__(1024) char smem[81920];
  const int tid = threadIdx.x;
  const int wave = tid >> 6, lane = tid & 63, quad = lane >> 4, l16 = lane & 15;
  const int wbase = tid & ~63;
  const int hloc = wave & 1, rgroup = wave >> 1;
  bf16* Pw = (bf16*)(smem + 65536) + wave * 1024;
  bf16x8 ones;
#pragma unroll
  for (int e = 0; e < 8; e++) ones[e] = (bf16)1.0f;

  const int w = blockIdx.x;
  const int side = w & 1, kvh = (w >> 1) & 7, b = (w >> 4) & 1, g = w >> 5;
  const int p = (g < 8) ? (2 * g + side) : (31 - 2 * (g - 8) - side);
  const int qt = (((kvh >> 2) ^ b) & 1) ? 31 - p : p;
  const int h = kvh * 2 + hloc;
  const int q0 = qt * 64;
  const int nkt = qt + 1;

#pragma unroll
  for (int u = 0; u < 4; u++) {
    int gg = u * 512 + tid;
    int row = gg >> 4, cc = gg & 15;
    const bf16* gp = QKV + (size_t)(b * 2048 + q0 + (row & 63)) * 4096 +
                     (kvh * 2 + (row >> 6)) * 128 + ((cc ^ (row & 15)) * 8);
    load16(gp, smem + (u * 512 + wbase) * 16);
  }
  asm volatile("s_waitcnt vmcnt(0)" ::: "memory");
  phase_barrier();
  bf16x8 aq[4];
  {
    int qr = hloc * 64 + rgroup * 16 + l16;
#pragma unroll
    for (int ks = 0; ks < 4; ks++)
      aq[ks] = *(const bf16x8*)((const bf16*)smem + qr * 128 +
                                (((ks * 4 + quad) ^ (qr & 15)) * 8));
  }
  __syncthreads();

  auto stageKV = [&](int kt, int nb) {
    char* kd = smem + nb * 16384;
    char* vd = smem + 32768 + nb * 16384;
#pragma unroll
    for (int u = 0; u < 2; u++) {
      int gg = u * 512 + tid;
      int krow = gg >> 4, kcc = gg & 15;
      const bf16* kp = QKV + (size_t)(b * 2048 + kt * 64 + krow) * 4096 + 2048 +
                       kvh * 128 + ((kcc ^ (krow & 15)) * 8);
      load16(kp, kd + (u * 512 + wbase) * 16);
      int vrow = gg >> 3, vcc = gg & 7;
      const bf16* vp = Vt + (size_t)(b * 1024 + kvh * 128 + vrow) * 2048 + kt * 64 +
                       ((vcc ^ (vrow & 7)) * 8);
      load16(vp, vd + (u * 512 + wbase) * 16);
    }
  };

  stageKV(0, 0);

  floatx4 oacc[8] = {};
  floatx4 lacc = {};
  const int q0w = q0 + rgroup * 16;

  for (int kt = 0; kt < nkt; kt++) {
    const int cur = kt & 1;
    if (kt + 1 < nkt) {
      stageKV(kt + 1, cur ^ 1);
      asm volatile("s_waitcnt vmcnt(4)" ::: "memory");
    } else {
      asm volatile("s_waitcnt vmcnt(0)" ::: "memory");
    }
    phase_barrier();
    const bf16* Kc = (const bf16*)(smem + cur * 16384);
    const bf16* Vc = (const bf16*)(smem + 32768 + cur * 16384);
    if (kt == nkt - 1)
      attn_step32<true>(Kc, Vc, Pw, aq, ones, oacc, lacc, kt * 64, q0w, l16, quad);
    else
      attn_step32<false>(Kc, Vc, Pw, aq, ones, oacc, lacc, kt * 64, q0w, l16, quad);
    phase_barrier();
  }

  float rl[4];
#pragma unroll
  for (int r = 0; r < 4; r++) rl[r] = 1.0f / lacc[r];
#pragma unroll
  for (int j = 0; j < 8; j++)
#pragma unroll
    for (int r = 0; r < 4; r++) {
      int s = q0w + quad * 4 + r;
      O[(size_t)(b * 2048 + s) * 2048 + h * 128 + j * 16 + l16] =
          (bf16)(oacc[j][r] * rl[r]);
    }
}

extern "C" void kernel_launch(void* const* d_in, const int* in_sizes, int n_in,
                              void* d_out, int out_size, void* d_ws, size_t ws_size,
                              hipStream_t stream) {
  (void)in_sizes; (void)n_in; (void)out_size; (void)ws_size;
  const float* x    = (const float*)d_in[0];
  const float* cosb = (const float*)d_in[1];
  const float* sinb = (const float*)d_in[2];
  const float* Wq   = (const float*)d_in[3];
  const float* Wk   = (const float*)d_in[4];
  const float* Wv   = (const float*)d_in[5];
  const float* Wo   = (const float*)d_in[6];
  float* out = (float*)d_out;

  char* ws = (char*)d_ws;
  size_t off = 0;
  auto alloc = [&](size_t bytes) { void* p = ws + off; off += bytes; return p; };
  bf16* xb    = (bf16*)alloc(4096ull * 2048 * 2);  // 16 MB
  bf16* WqkvT = (bf16*)alloc(4096ull * 2048 * 2);  // 16 MB  [Wq^T | Wk^T | Wv^T]
  bf16* WoT   = (bf16*)alloc(2048ull * 2048 * 2);  //  8 MB
  bf16* QKV   = (bf16*)alloc(4096ull * 4096 * 2);  // 32 MB  [s][Q 2048 | K 1024 | V 1024]
  bf16* Vtb   = (bf16*)alloc(2048ull * 2048 * 2);  //  8 MB  [b][kv*128+hd][s]
  bf16* Ab    = (bf16*)alloc(4096ull * 2048 * 2);  // 16 MB

  // 1. cvt + weight transposes (merged)
  prep_kernel<<<8192 + 16384, 256, 0, stream>>>(x, Wq, Wk, Wv, Wo, xb, WqkvT, WoT);

  // 2. fused QKV projection: A-tribuf deep-prefetch, 160KB LDS
  gemm256ta<bf16><<<dim3(16, 16), 512, 0, stream>>>(xb, WqkvT, QKV, 4096, 4096, 2048);

  // 3. RoPE + V transpose (merged)
  mid_kernel<<<24576 + 4096, 256, 0, stream>>>(QKV, cosb, sinb, Vtb);

  // 4. flash attention v9: CU-balanced qt map
  flash_kernel<<<dim3(512, 1, 1), 512, 0, stream>>>(QKV, Vtb, Ab);

  // 5. output projection: 256x128 tile -> 256 blocks (full GPU)
  gemm256x128<<<dim3(16, 16), 512, 0, stream>>>(Ab, WoT, out, 4096, 2048, 2048);
}